// Round 1
// baseline (351.492 us; speedup 1.0000x reference)
//
#include <hip/hip_runtime.h>
#include <hip/hip_bf16.h>
#include <math.h>

typedef short short8 __attribute__((ext_vector_type(8)));
typedef float f32x4 __attribute__((ext_vector_type(4)));
typedef unsigned short us4 __attribute__((ext_vector_type(4)));

#define QBF 127.0f
#define EPSF 1e-5f

#define BB 8
#define SS 32768
#define FF 128
#define K1 256
#define NROWS (BB * SS)      /* 262144 */
#define BM 64
#define NBLK (NROWS / BM)    /* 4096 */
#define TPB (SS / BM)        /* 512 tiles per batch */

static __device__ __forceinline__ unsigned short f2bf(float x) {
    // exact for all our values (small integers / +-1 / 0): low 16 bits are zero
    return (unsigned short)(__builtin_bit_cast(unsigned int, x) >> 16);
}

// ---------------- kernel 1: weight absmean (f64 accum) ----------------
__global__ void wstats_kernel(const float* __restrict__ W1,
                              const float* __restrict__ W2,
                              float* __restrict__ hdr) {
    __shared__ double red[256];
    int t = threadIdx.x;
    double s = 0.0;
    for (int i = t; i < 32768; i += 256) s += (double)fabsf(W1[i]);
    red[t] = s; __syncthreads();
    for (int o = 128; o > 0; o >>= 1) { if (t < o) red[t] += red[t + o]; __syncthreads(); }
    if (t == 0) {
        float mean1 = (float)(red[0] * (1.0 / 32768.0));
        hdr[0] = 1.0f / fmaxf(mean1, EPSF);          // ws1
    }
    __syncthreads();
    s = 0.0;
    for (int i = t; i < 16384; i += 256) s += (double)fabsf(W2[i]);
    red[t] = s; __syncthreads();
    for (int o = 128; o > 0; o >>= 1) { if (t < o) red[t] += red[t + o]; __syncthreads(); }
    if (t == 0) {
        float mean2 = (float)(red[0] * (1.0 / 16384.0));
        hdr[1] = 1.0f / fmaxf(mean2, EPSF);          // ws2
    }
}

// ---------------- kernel 2: ternary weight quant -> bf16 ----------------
__global__ void wquant_kernel(const float* __restrict__ W1,
                              const float* __restrict__ W2,
                              const float* __restrict__ hdr,
                              unsigned short* __restrict__ wq1,
                              unsigned short* __restrict__ wq2) {
    int i = blockIdx.x * 256 + threadIdx.x;
    float ws1 = hdr[0], ws2 = hdr[1];
    if (i < 32768) {
        float q = fminf(fmaxf(rintf(W1[i] * ws1), -1.f), 1.f);
        wq1[i] = f2bf(q);
    }
    if (i < 16384) {
        float q = fminf(fmaxf(rintf(W2[i] * ws2), -1.f), 1.f);
        wq2[i] = f2bf(q);
    }
}

// ---------------- kernel 3: fused main pass ----------------
__global__ __launch_bounds__(256, 2) void fused_kernel(
    const float* __restrict__ evid, const float* __restrict__ prior,
    const float* __restrict__ bias1, const float* __restrict__ bias2,
    const unsigned short* __restrict__ wq1, const unsigned short* __restrict__ wq2,
    const float* __restrict__ hdr, float* __restrict__ out,
    float* __restrict__ partials)
{
    __shared__ float prior_lds[BM][132];         // padded: epilogue reads conflict-free
    __shared__ unsigned short xq[BM * 256];      // bf16 bits; reused as hq[BM*128]
    __shared__ float rowS1[BM];
    __shared__ float rmax2[2][BM];
    __shared__ float colsum[4][64];

    const int tid = threadIdx.x;
    const int w = tid >> 6, l = tid & 63;
    const int rowbase = blockIdx.x * BM;

    // ---- Phase 1: load + per-row absmax 8-bit quantize (wave = one row/iter) ----
    {
        const float* src = (l < 32) ? prior : evid;   // concat([prior, evidence])
        const int lc = l & 31;
        #pragma unroll
        for (int i0 = 0; i0 < 16; i0 += 4) {
            float4 vv[4];
            #pragma unroll
            for (int i = 0; i < 4; ++i) {
                int row = w * 16 + i0 + i;
                vv[i] = *(const float4*)(src + (size_t)(rowbase + row) * FF + lc * 4);
            }
            #pragma unroll
            for (int i = 0; i < 4; ++i) {
                int row = w * 16 + i0 + i;
                float4 v = vv[i];
                if (l < 32) *(float4*)&prior_lds[row][lc * 4] = v;
                float m = fmaxf(fmaxf(fabsf(v.x), fabsf(v.y)),
                                fmaxf(fabsf(v.z), fabsf(v.w)));
                #pragma unroll
                for (int sh = 1; sh < 64; sh <<= 1) m = fmaxf(m, __shfl_xor(m, sh, 64));
                float s = QBF / fmaxf(m, EPSF);
                if (l == 0) rowS1[row] = s;
                us4 q;
                q.x = f2bf(fminf(fmaxf(rintf(v.x * s), -128.f), 127.f));
                q.y = f2bf(fminf(fmaxf(rintf(v.y * s), -128.f), 127.f));
                q.z = f2bf(fminf(fmaxf(rintf(v.z * s), -128.f), 127.f));
                q.w = f2bf(fminf(fmaxf(rintf(v.w * s), -128.f), 127.f));
                int byteoff = (row * 512 + l * 8) ^ ((row & 7) << 4);   // XOR swizzle (G4)
                *(us4*)((char*)xq + byteoff) = q;
            }
        }
    }
    __syncthreads();

    const int wm = w >> 1, wn = w & 1;     // wave quadrant: rows 32*wm, cols 64*wn
    const int lr = l & 15, lg = l >> 4;
    const float ws1 = hdr[0], ws2 = hdr[1];

    // ---- Layer-1 MFMA: [64 x 256] x [256 x 128] (exact integer math in bf16) ----
    f32x4 acc[2][4] = {};
    #pragma unroll
    for (int ks = 0; ks < 8; ++ks) {
        int row0 = 32 * wm + lr;
        int bo0 = (row0 * 512 + (ks * 32 + lg * 8) * 2) ^ ((row0 & 7) << 4);
        short8 a0 = *(const short8*)((const char*)xq + bo0);
        int row1 = row0 + 16;
        int bo1 = (row1 * 512 + (ks * 32 + lg * 8) * 2) ^ ((row1 & 7) << 4);
        short8 a1 = *(const short8*)((const char*)xq + bo1);
        #pragma unroll
        for (int ni = 0; ni < 4; ++ni) {
            int col = 64 * wn + 16 * ni + lr;
            short8 bfr = *(const short8*)(wq1 + col * K1 + ks * 32 + lg * 8);
            acc[0][ni] = __builtin_amdgcn_mfma_f32_16x16x32_bf16(a0, bfr, acc[0][ni], 0, 0, 0);
            acc[1][ni] = __builtin_amdgcn_mfma_f32_16x16x32_bf16(a1, bfr, acc[1][ni], 0, 0, 0);
        }
    }

    // ---- Epilogue 1: scale + bias + relu, row-max for requant ----
    float b1v[4];
    #pragma unroll
    for (int ni = 0; ni < 4; ++ni) b1v[ni] = bias1[64 * wn + 16 * ni + lr];

    float yv[2][4][4];
    float rmax[2][4];
    #pragma unroll
    for (int mi = 0; mi < 2; ++mi) {
        #pragma unroll
        for (int j = 0; j < 4; ++j) {
            int row = 32 * wm + 16 * mi + 4 * lg + j;
            float rinv = 1.0f / (rowS1[row] * ws1);
            float rm = 0.f;
            #pragma unroll
            for (int ni = 0; ni < 4; ++ni) {
                float y = acc[mi][ni][j] * rinv + b1v[ni];
                y = fmaxf(y, 0.f);
                yv[mi][ni][j] = y;
                rm = fmaxf(rm, y);
            }
            #pragma unroll
            for (int sh = 1; sh < 16; sh <<= 1) rm = fmaxf(rm, __shfl_xor(rm, sh, 64));
            rmax[mi][j] = rm;
        }
    }
    __syncthreads();   // all layer-1 LDS reads complete (xq about to be overwritten)
    if (lr == 0) {
        #pragma unroll
        for (int mi = 0; mi < 2; ++mi)
            #pragma unroll
            for (int j = 0; j < 4; ++j)
                rmax2[wn][32 * wm + 16 * mi + 4 * lg + j] = rmax[mi][j];
    }
    __syncthreads();

    // ---- Requantize h -> hq (reuse xq LDS, 256B rows, same XOR swizzle) ----
    float inv2[2][4];
    #pragma unroll
    for (int mi = 0; mi < 2; ++mi) {
        #pragma unroll
        for (int j = 0; j < 4; ++j) {
            int row = 32 * wm + 16 * mi + 4 * lg + j;
            float mx = fmaxf(rmax2[0][row], rmax2[1][row]);
            float s2 = QBF / fmaxf(mx, EPSF);
            inv2[mi][j] = 1.0f / (s2 * ws2);
            #pragma unroll
            for (int ni = 0; ni < 4; ++ni) {
                float q = fminf(fmaxf(rintf(yv[mi][ni][j] * s2), -128.f), 127.f);
                int col = 64 * wn + 16 * ni + lr;
                int bo = (row * 256 + col * 2) ^ ((row & 7) << 4);
                *(unsigned short*)((char*)xq + bo) = f2bf(q);
            }
        }
    }
    __syncthreads();

    // ---- Layer-2 MFMA: [64 x 128] x [128 x 128] ----
    f32x4 acc2[2][4] = {};
    #pragma unroll
    for (int ks = 0; ks < 4; ++ks) {
        int row0 = 32 * wm + lr;
        int co0 = (row0 * 256 + (ks * 32 + lg * 8) * 2) ^ ((row0 & 7) << 4);
        short8 a0 = *(const short8*)((const char*)xq + co0);
        int row1 = row0 + 16;
        int co1 = (row1 * 256 + (ks * 32 + lg * 8) * 2) ^ ((row1 & 7) << 4);
        short8 a1 = *(const short8*)((const char*)xq + co1);
        #pragma unroll
        for (int ni = 0; ni < 4; ++ni) {
            int col = 64 * wn + 16 * ni + lr;
            short8 bfr = *(const short8*)(wq2 + col * FF + ks * 32 + lg * 8);
            acc2[0][ni] = __builtin_amdgcn_mfma_f32_16x16x32_bf16(a0, bfr, acc2[0][ni], 0, 0, 0);
            acc2[1][ni] = __builtin_amdgcn_mfma_f32_16x16x32_bf16(a1, bfr, acc2[1][ni], 0, 0, 0);
        }
    }

    // ---- Epilogue 2: sigmoid, * prior, store unnorm, column partial sums ----
    float b2v[4];
    #pragma unroll
    for (int ni = 0; ni < 4; ++ni) b2v[ni] = bias2[64 * wn + 16 * ni + lr];

    float cs[4] = {0.f, 0.f, 0.f, 0.f};
    #pragma unroll
    for (int mi = 0; mi < 2; ++mi) {
        #pragma unroll
        for (int j = 0; j < 4; ++j) {
            int row = 32 * wm + 16 * mi + 4 * lg + j;
            #pragma unroll
            for (int ni = 0; ni < 4; ++ni) {
                int col = 64 * wn + 16 * ni + lr;
                float y = acc2[mi][ni][j] * inv2[mi][j] + b2v[ni];
                float lik = 1.0f / (1.0f + expf(-y));
                float un = prior_lds[row][col] * lik;
                out[(size_t)(rowbase + row) * FF + col] = un;
                cs[ni] += un;
            }
        }
    }
    #pragma unroll
    for (int ni = 0; ni < 4; ++ni) {
        cs[ni] += __shfl_xor(cs[ni], 16, 64);
        cs[ni] += __shfl_xor(cs[ni], 32, 64);
    }
    if (lg == 0) {
        #pragma unroll
        for (int ni = 0; ni < 4; ++ni) colsum[w][16 * ni + lr] = cs[ni];
    }
    __syncthreads();
    if (tid < 128) {
        int col = tid;
        float p = (col < 64) ? (colsum[0][col] + colsum[2][col])
                             : (colsum[1][col - 64] + colsum[3][col - 64]);
        partials[(size_t)blockIdx.x * FF + col] = p;
    }
}

// ---------------- kernel 4: deterministic normalizer reduction ----------------
__global__ void norm_kernel(const float* __restrict__ partials, float* __restrict__ norm) {
    __shared__ float red[4][128];
    int b = blockIdx.x;                          // 8 blocks
    int f = threadIdx.x & 127, tg = threadIdx.x >> 7;  // 512 threads
    float s = 0.f;
    for (int t = tg * 128; t < tg * 128 + 128; ++t)
        s += partials[((size_t)b * TPB + t) * FF + f];
    red[tg][f] = s; __syncthreads();
    if (tg == 0) {
        float tot = red[0][f] + red[1][f] + red[2][f] + red[3][f];
        norm[b * FF + f] = fmaxf(tot, 1e-10f);
    }
}

// ---------------- kernel 5: out /= norm ----------------
__global__ void div_kernel(float* __restrict__ out, const float* __restrict__ norm) {
    size_t i4 = (size_t)blockIdx.x * blockDim.x + threadIdx.x;
    const size_t total4 = (size_t)NROWS * FF / 4;
    for (; i4 < total4; i4 += (size_t)gridDim.x * blockDim.x) {
        size_t i = i4 * 4;
        float4 v = *(float4*)(out + i);
        int b = (int)(i >> 22);                  // S*F = 2^22
        int f = (int)(i & 127);
        float4 nv = *(const float4*)(norm + b * FF + f);
        v.x /= nv.x; v.y /= nv.y; v.z /= nv.z; v.w /= nv.w;
        *(float4*)(out + i) = v;
    }
}

extern "C" void kernel_launch(void* const* d_in, const int* in_sizes, int n_in,
                              void* d_out, int out_size, void* d_ws, size_t ws_size,
                              hipStream_t stream) {
    const float* evid  = (const float*)d_in[0];
    const float* prior = (const float*)d_in[1];
    const float* W1    = (const float*)d_in[2];
    const float* b1    = (const float*)d_in[3];
    const float* W2    = (const float*)d_in[4];
    const float* b2    = (const float*)d_in[5];
    float* out = (float*)d_out;

    char* ws = (char*)d_ws;
    float* hdr           = (float*)ws;                                  // 64 B
    unsigned short* wq1  = (unsigned short*)(ws + 256);                 // 64 KB
    unsigned short* wq2  = (unsigned short*)(ws + 256 + 65536);         // 32 KB
    float* partials      = (float*)(ws + 256 + 65536 + 32768);          // 2 MB
    float* norm          = (float*)(ws + 256 + 65536 + 32768 + 2097152);// 4 KB

    wstats_kernel<<<1, 256, 0, stream>>>(W1, W2, hdr);
    wquant_kernel<<<128, 256, 0, stream>>>(W1, W2, hdr, wq1, wq2);
    fused_kernel<<<NBLK, 256, 0, stream>>>(evid, prior, b1, b2, wq1, wq2, hdr, out, partials);
    norm_kernel<<<8, 512, 0, stream>>>(partials, norm);
    div_kernel<<<2048, 256, 0, stream>>>(out, norm);
}

// Round 2
// 252.578 us; speedup vs baseline: 1.3916x; 1.3916x over previous
//
#include <hip/hip_runtime.h>
#include <hip/hip_bf16.h>
#include <math.h>

typedef short short8 __attribute__((ext_vector_type(8)));
typedef float f32x4 __attribute__((ext_vector_type(4)));
typedef unsigned short us4 __attribute__((ext_vector_type(4)));

#define QBF 127.0f
#define EPSF 1e-5f

#define BB 8
#define SS 32768
#define FF 128
#define K1 256
#define NROWS (BB * SS)      /* 262144 */
#define BM 64
#define NBLK (NROWS / BM)    /* 4096 */
#define TPB (SS / BM)        /* 512 tiles per batch */

static __device__ __forceinline__ unsigned short f2bf(float x) {
    // exact for all our values (small integers / +-1 / 0): low 16 bits are zero
    return (unsigned short)(__builtin_bit_cast(unsigned int, x) >> 16);
}

// ---------------- kernel 1: weight absmean (f64 accum) ----------------
__global__ void wstats_kernel(const float* __restrict__ W1,
                              const float* __restrict__ W2,
                              float* __restrict__ hdr) {
    __shared__ double red[1024];
    int t = threadIdx.x;                         // 1024 threads
    // W1: 32768 elems = 8192 float4; 8 per thread
    double s = 0.0;
    #pragma unroll
    for (int i = 0; i < 8; ++i) {
        float4 v = *(const float4*)(W1 + (i * 1024 + t) * 4);
        s += (double)fabsf(v.x) + (double)fabsf(v.y)
           + (double)fabsf(v.z) + (double)fabsf(v.w);
    }
    red[t] = s; __syncthreads();
    for (int o = 512; o > 0; o >>= 1) { if (t < o) red[t] += red[t + o]; __syncthreads(); }
    if (t == 0) {
        float mean1 = (float)(red[0] * (1.0 / 32768.0));
        hdr[0] = 1.0f / fmaxf(mean1, EPSF);          // ws1
    }
    __syncthreads();
    // W2: 16384 elems = 4096 float4; 4 per thread
    s = 0.0;
    #pragma unroll
    for (int i = 0; i < 4; ++i) {
        float4 v = *(const float4*)(W2 + (i * 1024 + t) * 4);
        s += (double)fabsf(v.x) + (double)fabsf(v.y)
           + (double)fabsf(v.z) + (double)fabsf(v.w);
    }
    red[t] = s; __syncthreads();
    for (int o = 512; o > 0; o >>= 1) { if (t < o) red[t] += red[t + o]; __syncthreads(); }
    if (t == 0) {
        float mean2 = (float)(red[0] * (1.0 / 16384.0));
        hdr[1] = 1.0f / fmaxf(mean2, EPSF);          // ws2
    }
}

// ---------------- kernel 2: ternary weight quant -> bf16 ----------------
__global__ void wquant_kernel(const float* __restrict__ W1,
                              const float* __restrict__ W2,
                              const float* __restrict__ hdr,
                              unsigned short* __restrict__ wq1,
                              unsigned short* __restrict__ wq2) {
    int i = blockIdx.x * 256 + threadIdx.x;
    float ws1 = hdr[0], ws2 = hdr[1];
    if (i < 32768) {
        float q = fminf(fmaxf(rintf(W1[i] * ws1), -1.f), 1.f);
        wq1[i] = f2bf(q);
    }
    if (i < 16384) {
        float q = fminf(fmaxf(rintf(W2[i] * ws2), -1.f), 1.f);
        wq2[i] = f2bf(q);
    }
}

// ---------------- kernel 3: fused main pass ----------------
// LDS ~34.5 KB -> 4 blocks/CU (16 waves/CU). prior is re-read from global in
// the epilogue (L2/L3-hot) instead of burning 33.8 KB of LDS on it.
__global__ __launch_bounds__(256, 4) void fused_kernel(
    const float* __restrict__ evid, const float* __restrict__ prior,
    const float* __restrict__ bias1, const float* __restrict__ bias2,
    const unsigned short* __restrict__ wq1, const unsigned short* __restrict__ wq2,
    const float* __restrict__ hdr, float* __restrict__ out,
    float* __restrict__ partials)
{
    __shared__ unsigned short xq[BM * 256];      // bf16 bits; reused as hq[BM*128]
    __shared__ float rowS1[BM];
    __shared__ float rmax2[2][BM];
    __shared__ float colsum[4][64];

    const int tid = threadIdx.x;
    const int w = tid >> 6, l = tid & 63;
    const int rowbase = blockIdx.x * BM;

    // ---- Phase 1: load + per-row absmax 8-bit quantize (wave = one row/iter) ----
    {
        const float* src = (l < 32) ? prior : evid;   // concat([prior, evidence])
        const int lc = l & 31;
        #pragma unroll
        for (int i0 = 0; i0 < 16; i0 += 4) {
            float4 vv[4];
            #pragma unroll
            for (int i = 0; i < 4; ++i) {
                int row = w * 16 + i0 + i;
                vv[i] = *(const float4*)(src + (size_t)(rowbase + row) * FF + lc * 4);
            }
            #pragma unroll
            for (int i = 0; i < 4; ++i) {
                int row = w * 16 + i0 + i;
                float4 v = vv[i];
                float m = fmaxf(fmaxf(fabsf(v.x), fabsf(v.y)),
                                fmaxf(fabsf(v.z), fabsf(v.w)));
                #pragma unroll
                for (int sh = 1; sh < 64; sh <<= 1) m = fmaxf(m, __shfl_xor(m, sh, 64));
                float s = QBF / fmaxf(m, EPSF);
                if (l == 0) rowS1[row] = s;
                us4 q;
                q.x = f2bf(fminf(fmaxf(rintf(v.x * s), -128.f), 127.f));
                q.y = f2bf(fminf(fmaxf(rintf(v.y * s), -128.f), 127.f));
                q.z = f2bf(fminf(fmaxf(rintf(v.z * s), -128.f), 127.f));
                q.w = f2bf(fminf(fmaxf(rintf(v.w * s), -128.f), 127.f));
                int byteoff = (row * 512 + l * 8) ^ ((row & 7) << 4);   // XOR swizzle (G4)
                *(us4*)((char*)xq + byteoff) = q;
            }
        }
    }
    __syncthreads();

    const int wm = w >> 1, wn = w & 1;     // wave quadrant: rows 32*wm, cols 64*wn
    const int lr = l & 15, lg = l >> 4;
    const float ws1 = hdr[0], ws2 = hdr[1];

    // ---- Layer-1 MFMA: [64 x 256] x [256 x 128] (exact integer math in bf16) ----
    f32x4 acc[2][4] = {};
    #pragma unroll
    for (int ks = 0; ks < 8; ++ks) {
        int row0 = 32 * wm + lr;
        int bo0 = (row0 * 512 + (ks * 32 + lg * 8) * 2) ^ ((row0 & 7) << 4);
        short8 a0 = *(const short8*)((const char*)xq + bo0);
        int row1 = row0 + 16;
        int bo1 = (row1 * 512 + (ks * 32 + lg * 8) * 2) ^ ((row1 & 7) << 4);
        short8 a1 = *(const short8*)((const char*)xq + bo1);
        #pragma unroll
        for (int ni = 0; ni < 4; ++ni) {
            int col = 64 * wn + 16 * ni + lr;
            short8 bfr = *(const short8*)(wq1 + col * K1 + ks * 32 + lg * 8);
            acc[0][ni] = __builtin_amdgcn_mfma_f32_16x16x32_bf16(a0, bfr, acc[0][ni], 0, 0, 0);
            acc[1][ni] = __builtin_amdgcn_mfma_f32_16x16x32_bf16(a1, bfr, acc[1][ni], 0, 0, 0);
        }
    }

    // ---- Epilogue 1: scale + bias + relu, row-max for requant ----
    float b1v[4];
    #pragma unroll
    for (int ni = 0; ni < 4; ++ni) b1v[ni] = bias1[64 * wn + 16 * ni + lr];

    float yv[2][4][4];
    #pragma unroll
    for (int mi = 0; mi < 2; ++mi) {
        #pragma unroll
        for (int j = 0; j < 4; ++j) {
            int row = 32 * wm + 16 * mi + 4 * lg + j;
            float rinv = 1.0f / (rowS1[row] * ws1);
            float rm = 0.f;
            #pragma unroll
            for (int ni = 0; ni < 4; ++ni) {
                float y = acc[mi][ni][j] * rinv + b1v[ni];
                y = fmaxf(y, 0.f);
                yv[mi][ni][j] = y;
                rm = fmaxf(rm, y);
            }
            #pragma unroll
            for (int sh = 1; sh < 16; sh <<= 1) rm = fmaxf(rm, __shfl_xor(rm, sh, 64));
            if (lr == 0) rmax2[wn][row] = rm;
        }
    }
    __syncthreads();   // xq layer-1 reads done AND rmax2 visible

    // ---- Requantize h -> hq (reuse xq LDS, 256B rows, same XOR swizzle) ----
    float inv2[2][4];
    #pragma unroll
    for (int mi = 0; mi < 2; ++mi) {
        #pragma unroll
        for (int j = 0; j < 4; ++j) {
            int row = 32 * wm + 16 * mi + 4 * lg + j;
            float mx = fmaxf(rmax2[0][row], rmax2[1][row]);
            float s2 = QBF / fmaxf(mx, EPSF);
            inv2[mi][j] = 1.0f / (s2 * ws2);
            #pragma unroll
            for (int ni = 0; ni < 4; ++ni) {
                float q = fminf(fmaxf(rintf(yv[mi][ni][j] * s2), -128.f), 127.f);
                int col = 64 * wn + 16 * ni + lr;
                int bo = (row * 256 + col * 2) ^ ((row & 7) << 4);
                *(unsigned short*)((char*)xq + bo) = f2bf(q);
            }
        }
    }
    __syncthreads();

    // ---- Layer-2 MFMA: [64 x 128] x [128 x 128] ----
    f32x4 acc2[2][4] = {};
    #pragma unroll
    for (int ks = 0; ks < 4; ++ks) {
        int row0 = 32 * wm + lr;
        int co0 = (row0 * 256 + (ks * 32 + lg * 8) * 2) ^ ((row0 & 7) << 4);
        short8 a0 = *(const short8*)((const char*)xq + co0);
        int row1 = row0 + 16;
        int co1 = (row1 * 256 + (ks * 32 + lg * 8) * 2) ^ ((row1 & 7) << 4);
        short8 a1 = *(const short8*)((const char*)xq + co1);
        #pragma unroll
        for (int ni = 0; ni < 4; ++ni) {
            int col = 64 * wn + 16 * ni + lr;
            short8 bfr = *(const short8*)(wq2 + col * FF + ks * 32 + lg * 8);
            acc2[0][ni] = __builtin_amdgcn_mfma_f32_16x16x32_bf16(a0, bfr, acc2[0][ni], 0, 0, 0);
            acc2[1][ni] = __builtin_amdgcn_mfma_f32_16x16x32_bf16(a1, bfr, acc2[1][ni], 0, 0, 0);
        }
    }

    // ---- Epilogue 2: sigmoid, * prior (re-read, L2/L3-hot), store, col sums ----
    float b2v[4];
    #pragma unroll
    for (int ni = 0; ni < 4; ++ni) b2v[ni] = bias2[64 * wn + 16 * ni + lr];

    float cs[4] = {0.f, 0.f, 0.f, 0.f};
    #pragma unroll
    for (int mi = 0; mi < 2; ++mi) {
        #pragma unroll
        for (int j = 0; j < 4; ++j) {
            int row = 32 * wm + 16 * mi + 4 * lg + j;
            const float* prow = prior + (size_t)(rowbase + row) * FF;
            float pv[4];
            #pragma unroll
            for (int ni = 0; ni < 4; ++ni) pv[ni] = prow[64 * wn + 16 * ni + lr];
            #pragma unroll
            for (int ni = 0; ni < 4; ++ni) {
                int col = 64 * wn + 16 * ni + lr;
                float y = acc2[mi][ni][j] * inv2[mi][j] + b2v[ni];
                float lik = 1.0f / (1.0f + __expf(-y));
                float un = pv[ni] * lik;
                out[(size_t)(rowbase + row) * FF + col] = un;
                cs[ni] += un;
            }
        }
    }
    #pragma unroll
    for (int ni = 0; ni < 4; ++ni) {
        cs[ni] += __shfl_xor(cs[ni], 16, 64);
        cs[ni] += __shfl_xor(cs[ni], 32, 64);
    }
    if (lg == 0) {
        #pragma unroll
        for (int ni = 0; ni < 4; ++ni) colsum[w][16 * ni + lr] = cs[ni];
    }
    __syncthreads();
    if (tid < 128) {
        int col = tid;
        float p = (col < 64) ? (colsum[0][col] + colsum[2][col])
                             : (colsum[1][col - 64] + colsum[3][col - 64]);
        partials[(size_t)blockIdx.x * FF + col] = p;
    }
}

// ---------------- kernel 4: deterministic normalizer reduction ----------------
__global__ void norm_kernel(const float* __restrict__ partials, float* __restrict__ norm) {
    __shared__ float red[4][128];
    int b = blockIdx.x;                          // 8 blocks
    int f = threadIdx.x & 127, tg = threadIdx.x >> 7;  // 512 threads
    float s = 0.f;
    for (int t = tg * 128; t < tg * 128 + 128; ++t)
        s += partials[((size_t)b * TPB + t) * FF + f];
    red[tg][f] = s; __syncthreads();
    if (tg == 0) {
        float tot = red[0][f] + red[1][f] + red[2][f] + red[3][f];
        norm[b * FF + f] = fmaxf(tot, 1e-10f);
    }
}

// ---------------- kernel 5: out /= norm ----------------
__global__ void div_kernel(float* __restrict__ out, const float* __restrict__ norm) {
    size_t i4 = (size_t)blockIdx.x * blockDim.x + threadIdx.x;
    const size_t total4 = (size_t)NROWS * FF / 4;
    for (; i4 < total4; i4 += (size_t)gridDim.x * blockDim.x) {
        size_t i = i4 * 4;
        float4 v = *(float4*)(out + i);
        int b = (int)(i >> 22);                  // S*F = 2^22
        int f = (int)(i & 127);
        float4 nv = *(const float4*)(norm + b * FF + f);
        v.x /= nv.x; v.y /= nv.y; v.z /= nv.z; v.w /= nv.w;
        *(float4*)(out + i) = v;
    }
}

extern "C" void kernel_launch(void* const* d_in, const int* in_sizes, int n_in,
                              void* d_out, int out_size, void* d_ws, size_t ws_size,
                              hipStream_t stream) {
    const float* evid  = (const float*)d_in[0];
    const float* prior = (const float*)d_in[1];
    const float* W1    = (const float*)d_in[2];
    const float* b1    = (const float*)d_in[3];
    const float* W2    = (const float*)d_in[4];
    const float* b2    = (const float*)d_in[5];
    float* out = (float*)d_out;

    char* ws = (char*)d_ws;
    float* hdr           = (float*)ws;                                  // 64 B
    unsigned short* wq1  = (unsigned short*)(ws + 256);                 // 64 KB
    unsigned short* wq2  = (unsigned short*)(ws + 256 + 65536);         // 32 KB
    float* partials      = (float*)(ws + 256 + 65536 + 32768);          // 2 MB
    float* norm          = (float*)(ws + 256 + 65536 + 32768 + 2097152);// 4 KB

    wstats_kernel<<<1, 1024, 0, stream>>>(W1, W2, hdr);
    wquant_kernel<<<128, 256, 0, stream>>>(W1, W2, hdr, wq1, wq2);
    fused_kernel<<<NBLK, 256, 0, stream>>>(evid, prior, b1, b2, wq1, wq2, hdr, out, partials);
    norm_kernel<<<8, 512, 0, stream>>>(partials, norm);
    div_kernel<<<2048, 256, 0, stream>>>(out, norm);
}